// Round 5
// baseline (199.292 us; speedup 1.0000x reference)
//
#include <hip/hip_runtime.h>

// InfoNCE loss:
//   loss = (1/B) * sum_i [ log(sum_j exp(Q_i . D_j / T)) - Q_i . D_{i*dp} / T ]
// Logits bounded (|logit| < ~10) -> no max-subtraction; per-row sum-exp is
// commutative -> atomicAdd merge across column-blocks.
//
// R5 changes vs R4 (which passed, GEMM 44.7us / 1537 TF, conflicts 0):
//  - cvt inverted: one thread per 16 CONSECUTIVE input floats (reads fully
//    coalesced, 64B/lane, one wave = one 4KB row); output slot computed
//    arithmetically (writes 16B-scattered but only 12MB, L2-absorbed).
//    Produces byte-identical fp8 buffers to R4's cvt.
//  - final_kernel fused into gemm via last-block-done (threadfence +
//    device-scope counter, counter zeroed by cvt): 3 dispatches -> 2.
//
// Tiled layout (per matrix): for 128-row block R, 128-wide k-block k0b:
//   16KB image = 16 chunks x 1KB. Chunk c = rg*2 + kh (rg=0..7 16-row group,
//   kh=0..1 64-col half); slot l (16B) holds
//   X[R*128 + rg*16 + (l&15)][k0b*128 + kh*64 + (l>>4)*16 .. +16]   (fp8)
//
// ws layout (~12.1 MB):
//   [0)       Q8  B*K fp8     (4 MB)
//   [B*K)     D8  N*K fp8     (8 MB)
//   [+N*K)    rowsum B f32    (16 KB)  zeroed by cvt kernel
//   [+B*4)    pos    B f32    (16 KB)  written by gemm epilogue
//   [+B*4)    cnt    1 u32             zeroed by cvt kernel

#define TEMP_INV 50.0f
#define PRESCALE 16.0f
#define SCALE_BYTE 123   // e8m0: 2^(123-127) = 2^-4 per operand
#define KD 1024          // DIM (fixed by problem shape)

typedef int   i32x4 __attribute__((ext_vector_type(4)));
typedef int   i32x8 __attribute__((ext_vector_type(8)));
typedef float f32x4 __attribute__((ext_vector_type(4)));

// ---------------- fp32 -> fp8 e4m3 (x16), pre-tiled; zero rowsum+cnt -------
// Thread = 16 consecutive input floats (64B, coalesced). Output slot:
//   r = row, kk = col base; k0b=kk>>7, kh=(kk>>6)&1, kq=(kk>>4)&3,
//   R=r>>7, rg=(r>>4)&7, lr=r&15
//   dword off = (R*8+k0b)*4096 + (rg*2+kh)*256 + (kq*16+lr)*4
__global__ void cvt_kernel(const float* __restrict__ Q, const float* __restrict__ Dm,
                           unsigned int* __restrict__ Q8, unsigned int* __restrict__ D8,
                           float* __restrict__ rowsum, unsigned int* __restrict__ cnt,
                           int qThreads, int B) {
    const int gid = blockIdx.x * blockDim.x + threadIdx.x;
    if (gid < B) rowsum[gid] = 0.0f;
    if (gid == 0) cnt[0] = 0u;
    const float* src;
    unsigned int* dst;
    int f;
    if (gid < qThreads) { src = Q;  dst = Q8; f = gid * 16; }
    else                { src = Dm; dst = D8; f = (gid - qThreads) * 16; }
    const int r  = f >> 10;          // KD = 1024
    const int kk = f & 1023;
    const int k0b = kk >> 7;
    const int kh  = (kk >> 6) & 1;
    const int kq  = (kk >> 4) & 3;
    const int R   = r >> 7;
    const int rg  = (r >> 4) & 7;
    const int lr  = r & 15;
    const size_t off = (size_t)(R * 8 + k0b) * 4096 + (rg * 2 + kh) * 256
                     + (kq * 16 + lr) * 4;
    const float* p = src + (size_t)f;
    unsigned int w[4];
#pragma unroll
    for (int d = 0; d < 4; ++d) {
        float4 v = *(const float4*)(p + d * 4);
        int t = __builtin_amdgcn_cvt_pk_fp8_f32(v.x * PRESCALE, v.y * PRESCALE, 0, false);
        t = __builtin_amdgcn_cvt_pk_fp8_f32(v.z * PRESCALE, v.w * PRESCALE, t, true);
        w[d] = (unsigned int)t;
    }
    *(uint4*)(dst + off) = make_uint4(w[0], w[1], w[2], w[3]);
}

// ---------------- fused MX-fp8 GEMM + row sum-exp + pos + final ------------
// grid (B/128, N/128), 256 threads (4 waves, 2x2 wave grid), BK=128.
__global__ __launch_bounds__(256, 2) void gemm_expsum_kernel(
        const unsigned int* __restrict__ Q8, const unsigned int* __restrict__ D8,
        const int* __restrict__ dper,
        float* __restrict__ rowsum, float* __restrict__ pos,
        unsigned int* __restrict__ cnt, float* __restrict__ out,
        int B, int K) {
    __shared__ unsigned int Qs[4096];   // 16KB fragment-order image
    __shared__ unsigned int Ds[4096];
    __shared__ float redf[4];
    __shared__ int amLastS;

    const int tid   = threadIdx.x;
    const int wave  = tid >> 6;
    const int lane  = tid & 63;
    const int lquad = lane >> 4;
    const int lm    = lane & 15;
    const int qbase = blockIdx.x * 128;
    const int dbase = blockIdx.y * 128;
    const int KB    = K >> 7;           // 8 k-blocks

    // fragment-read dword offsets: chunk(rg, kh=lquad>>1)*256 + slot*4,
    // slot = ((lquad&1)*2 + t)*16 + lm
    const int slotofs = ((lquad & 1) * 32 + lm) * 4;   // t=0; t=1 adds 64
    const int aofs = ((wave >> 1) * 8 + (lquad >> 1)) * 256 + slotofs;
    const int bofs = ((wave & 1) * 8 + (lquad >> 1)) * 256 + slotofs;

    const unsigned int* Qg = Q8 + (size_t)blockIdx.x * KB * 4096;
    const unsigned int* Dg = D8 + (size_t)blockIdx.y * KB * 4096;

    f32x4 acc[16];
#pragma unroll
    for (int t = 0; t < 16; ++t) acc[t] = (f32x4){0.f, 0.f, 0.f, 0.f};

    for (int kb = 0; kb < KB; ++kb) {
#pragma unroll
        for (int q = 0; q < 4; ++q) {
            const int c = wave * 4 + q;
            const unsigned int* g1 = Qg + kb * 4096 + c * 256 + lane * 4;
            __builtin_amdgcn_global_load_lds(
                (const __attribute__((address_space(1))) void*)g1,
                (__attribute__((address_space(3))) void*)(Qs + c * 256 + lane * 4),
                16, 0, 0);
            const unsigned int* g2 = Dg + kb * 4096 + c * 256 + lane * 4;
            __builtin_amdgcn_global_load_lds(
                (const __attribute__((address_space(1))) void*)g2,
                (__attribute__((address_space(3))) void*)(Ds + c * 256 + lane * 4),
                16, 0, 0);
        }
        __syncthreads();   // drains vmcnt -> LDS tiles ready

        i32x8 a8[4], b8[4];
#pragma unroll
        for (int i = 0; i < 4; ++i) {
            i32x4 lo = *(const i32x4*)(Qs + aofs + i * 512);
            i32x4 hi = *(const i32x4*)(Qs + aofs + i * 512 + 64);
            a8[i] = __builtin_shufflevector(lo, hi, 0, 1, 2, 3, 4, 5, 6, 7);
        }
#pragma unroll
        for (int j = 0; j < 4; ++j) {
            i32x4 lo = *(const i32x4*)(Ds + bofs + j * 512);
            i32x4 hi = *(const i32x4*)(Ds + bofs + j * 512 + 64);
            b8[j] = __builtin_shufflevector(lo, hi, 0, 1, 2, 3, 4, 5, 6, 7);
        }
#pragma unroll
        for (int i = 0; i < 4; ++i)
#pragma unroll
            for (int j = 0; j < 4; ++j)
                acc[i * 4 + j] = __builtin_amdgcn_mfma_scale_f32_16x16x128_f8f6f4(
                    a8[i], b8[j], acc[i * 4 + j], 0, 0, 0, SCALE_BYTE, 0, SCALE_BYTE);
        __syncthreads();   // all waves done reading before next stage
    }

    // epilogue. C layout: col = lane&15, row = (lane>>4)*4 + reg (16x16 shape)
    const int dp = dper[0];
#pragma unroll
    for (int i = 0; i < 4; ++i)
#pragma unroll
        for (int r = 0; r < 4; ++r) {
            const int gr   = qbase + (wave >> 1) * 64 + 16 * i + 4 * lquad + r;
            const int pcol = gr * dp - dbase;   // local col of positive, if here
            float e = 0.0f;
#pragma unroll
            for (int j = 0; j < 4; ++j) {
                float v = acc[i * 4 + j][r];
                if ((wave & 1) * 64 + 16 * j + lm == pcol) pos[gr] = v * TEMP_INV;
                e += __expf(v * TEMP_INV);
            }
            e += __shfl_xor(e, 1);
            e += __shfl_xor(e, 2);
            e += __shfl_xor(e, 4);
            e += __shfl_xor(e, 8);
            if (lm == 0) atomicAdd(&rowsum[gr], e);
        }

    // ---- fused final: last block to finish computes the loss ----
    __syncthreads();
    if (tid == 0) {
        __threadfence();   // release our pos stores + rowsum atomics
        unsigned int old = __hip_atomic_fetch_add(cnt, 1u, __ATOMIC_ACQ_REL,
                                                  __HIP_MEMORY_SCOPE_AGENT);
        amLastS = (old == gridDim.x * gridDim.y - 1) ? 1 : 0;
    }
    __syncthreads();
    if (amLastS) {
        float s = 0.0f;
        for (int i = tid; i < B; i += 256) {
            float rs = __hip_atomic_load(&rowsum[i], __ATOMIC_RELAXED,
                                         __HIP_MEMORY_SCOPE_AGENT);
            float ps = __hip_atomic_load(&pos[i], __ATOMIC_RELAXED,
                                         __HIP_MEMORY_SCOPE_AGENT);
            s += __logf(rs) - ps;
        }
        s += __shfl_xor(s, 32);
        s += __shfl_xor(s, 16);
        s += __shfl_xor(s, 8);
        s += __shfl_xor(s, 4);
        s += __shfl_xor(s, 2);
        s += __shfl_xor(s, 1);
        if (lane == 0) redf[wave] = s;
        __syncthreads();
        if (tid == 0)
            out[0] = (redf[0] + redf[1] + redf[2] + redf[3]) / (float)B;
    }
}

extern "C" void kernel_launch(void* const* d_in, const int* in_sizes, int n_in,
                              void* d_out, int out_size, void* d_ws, size_t ws_size,
                              hipStream_t stream) {
    const float* Q   = (const float*)d_in[0];
    const float* Dm  = (const float*)d_in[1];
    const int* dper  = (const int*)d_in[2];
    float* out = (float*)d_out;

    const int DIM  = KD;
    const int B    = in_sizes[0] / DIM;   // 4096
    const int Ntot = in_sizes[1] / DIM;   // 8192

    unsigned int* Q8 = (unsigned int*)d_ws;
    unsigned int* D8 = Q8 + (size_t)B * DIM / 4;
    float* rowsum = (float*)(D8 + (size_t)Ntot * DIM / 4);
    float* pos = rowsum + B;
    unsigned int* cnt = (unsigned int*)(pos + B);

    const int qThreads = B * DIM / 16;          // 262144
    const int dThreads = Ntot * DIM / 16;       // 524288
    cvt_kernel<<<(qThreads + dThreads) / 256, 256, 0, stream>>>(
        Q, Dm, Q8, D8, rowsum, cnt, qThreads, B);

    dim3 grid(B / 128, Ntot / 128);
    gemm_expsum_kernel<<<grid, 256, 0, stream>>>(Q8, D8, dper, rowsum, pos,
                                                 cnt, out, B, DIM);
}

// Round 6
// 149.797 us; speedup vs baseline: 1.3304x; 1.3304x over previous
//
#include <hip/hip_runtime.h>

// InfoNCE loss:
//   loss = (1/B) * sum_i [ log(sum_j exp(Q_i . D_j / T)) - Q_i . D_{i*dp} / T ]
// Logits bounded (|logit| < ~10) -> no max-subtraction; per-row sum-exp is
// commutative -> atomicAdd merge across column-blocks.
//
// R6 = R4 structure (3 dispatches, NO per-block device fences -- R5 showed
// those invalidate per-XCD L2 and 2.5x the GEMM) + bigger GEMM tile:
//  - 128x256 tile, 512 threads (8 waves, 2x4 wave grid), BK=128.
//    Staging 48KB/8 waves = 6KB/wave for 16 MFMA/wave -> compute:staging
//    2.67 vs R4's 2.0. Per-wave fragment/epilogue math identical to R4
//    (verified absmax 0.0); only wave-grid + staging assignment generalized.
//
// Tiled layout (per matrix): for 128-row block R, 128-wide k-block k0b:
//   16KB image = 16 chunks x 1KB. Chunk c = rg*2 + kh (rg=0..7 16-row group,
//   kh=0..1 64-col half); slot l (16B) holds
//   X[R*128 + rg*16 + (l&15)][k0b*128 + kh*64 + (l>>4)*16 .. +16]   (fp8)
//
// ws layout (~12.1 MB):
//   [0)       Q8  B*K fp8     (4 MB)
//   [B*K)     D8  N*K fp8     (8 MB)
//   [+N*K)    rowsum B f32    (16 KB)  zeroed by cvt kernel
//   [+B*4)    pos    B f32    (16 KB)  written by gemm epilogue

#define TEMP_INV 50.0f
#define PRESCALE 16.0f
#define SCALE_BYTE 123   // e8m0: 2^(123-127) = 2^-4 per operand
#define KD 1024          // DIM (fixed by problem shape)

typedef int   i32x4 __attribute__((ext_vector_type(4)));
typedef int   i32x8 __attribute__((ext_vector_type(8)));
typedef float f32x4 __attribute__((ext_vector_type(4)));

// ---------------- fp32 -> fp8 e4m3 (x16), pre-tiled; zero rowsum ----------
// One thread per 16B output slot (R4's verified cvt). Output stores are
// lane-linear; input reads are 64B/lane (4x float4, full-line utilization).
__global__ void cvt_kernel(const float* __restrict__ Q, const float* __restrict__ Dm,
                           unsigned int* __restrict__ Q8, unsigned int* __restrict__ D8,
                           float* __restrict__ rowsum, int qSlots, int B, int K) {
    const int gid = blockIdx.x * blockDim.x + threadIdx.x;
    if (gid < B) rowsum[gid] = 0.0f;
    const float* src;
    unsigned int* dst;
    int s;
    if (gid < qSlots) { src = Q;  dst = Q8; s = gid; }
    else              { src = Dm; dst = D8; s = gid - qSlots; }
    const int l   = s & 63;
    const int c   = (s >> 6) & 15;
    const int k0b = (s >> 10) & 7;
    const int R   = s >> 13;
    const int row = R * 128 + (c >> 1) * 16 + (l & 15);
    const int k   = k0b * 128 + (c & 1) * 64 + (l >> 4) * 16;
    const float* p = src + (size_t)row * K + k;
    unsigned int w[4];
#pragma unroll
    for (int d = 0; d < 4; ++d) {
        float4 v = *(const float4*)(p + d * 4);
        int t = __builtin_amdgcn_cvt_pk_fp8_f32(v.x * PRESCALE, v.y * PRESCALE, 0, false);
        t = __builtin_amdgcn_cvt_pk_fp8_f32(v.z * PRESCALE, v.w * PRESCALE, t, true);
        w[d] = (unsigned int)t;
    }
    *(uint4*)(dst + (size_t)s * 4) = make_uint4(w[0], w[1], w[2], w[3]);
}

// ---------------- fused MX-fp8 GEMM + row sum-exp + pos extraction --------
// grid (B/128, N/256), 512 threads (8 waves, wave grid 2 rows x 4 cols).
// Q tile 128x1024-K staged per 128-k-block (16KB); D tile 256 rows as two
// 128-row images (2x16KB). 48 chunk-loads/K-block, 6 per wave.
__global__ __launch_bounds__(512, 2) void gemm_expsum_kernel(
        const unsigned int* __restrict__ Q8, const unsigned int* __restrict__ D8,
        const int* __restrict__ dper,
        float* __restrict__ rowsum, float* __restrict__ pos, int K) {
    __shared__ unsigned int Qs[4096];   // 16KB: one 128-row fragment image
    __shared__ unsigned int Ds[8192];   // 32KB: two 128-row fragment images

    const int tid   = threadIdx.x;
    const int wave  = tid >> 6;          // 0..7
    const int lane  = tid & 63;
    const int lquad = lane >> 4;
    const int lm    = lane & 15;
    const int wr    = wave >> 2;         // 0..1: 64-row quadrant
    const int wc    = wave & 3;          // 0..3: 64-col quadrant
    const int qbase = blockIdx.x * 128;
    const int dbase = blockIdx.y * 256;
    const int KB    = K >> 7;            // 8 k-blocks

    // fragment-read dword offsets (same algebra as R4, verified absmax 0.0):
    // slot = ((lquad&1)*2 + t)*16 + lm, chunk(rg, kh=lquad>>1)
    const int slotofs = ((lquad & 1) * 32 + lm) * 4;   // t=0; t=1 adds 64
    const int aofs = wr * 2048 + (lquad >> 1) * 256 + slotofs;
    const int bofs = wc * 2048 + (lquad >> 1) * 256 + slotofs;  // img in bit 1 of wc

    const unsigned int* Qg = Q8 + (size_t)blockIdx.x * KB * 4096;
    const unsigned int* Dg = D8 + (size_t)blockIdx.y * 2 * KB * 4096;

    f32x4 acc[16];
#pragma unroll
    for (int t = 0; t < 16; ++t) acc[t] = (f32x4){0.f, 0.f, 0.f, 0.f};

    for (int kb = 0; kb < KB; ++kb) {
#pragma unroll
        for (int q = 0; q < 6; ++q) {
            const int c6 = wave * 6 + q;          // 0..47, wave-uniform
            const unsigned int* src;
            unsigned int* dst;
            if (c6 < 16) {                         // Q image, chunk c6
                src = Qg + kb * 4096 + c6 * 256 + lane * 4;
                dst = (unsigned int*)Qs + c6 * 256 + lane * 4;
            } else if (c6 < 32) {                  // D image A, chunk c6-16
                const int cc = c6 - 16;
                src = Dg + kb * 4096 + cc * 256 + lane * 4;
                dst = (unsigned int*)Ds + cc * 256 + lane * 4;
            } else {                               // D image B, chunk c6-32
                const int cc = c6 - 32;
                src = Dg + (size_t)KB * 4096 + kb * 4096 + cc * 256 + lane * 4;
                dst = (unsigned int*)Ds + 4096 + cc * 256 + lane * 4;
            }
            __builtin_amdgcn_global_load_lds(
                (const __attribute__((address_space(1))) void*)src,
                (__attribute__((address_space(3))) void*)dst, 16, 0, 0);
        }
        __syncthreads();   // drains vmcnt -> LDS tiles ready

        i32x8 a8[4], b8[4];
#pragma unroll
        for (int i = 0; i < 4; ++i) {
            i32x4 lo = *(const i32x4*)(Qs + aofs + i * 512);
            i32x4 hi = *(const i32x4*)(Qs + aofs + i * 512 + 64);
            a8[i] = __builtin_shufflevector(lo, hi, 0, 1, 2, 3, 4, 5, 6, 7);
        }
#pragma unroll
        for (int j = 0; j < 4; ++j) {
            i32x4 lo = *(const i32x4*)(Ds + bofs + j * 512);
            i32x4 hi = *(const i32x4*)(Ds + bofs + j * 512 + 64);
            b8[j] = __builtin_shufflevector(lo, hi, 0, 1, 2, 3, 4, 5, 6, 7);
        }
#pragma unroll
        for (int i = 0; i < 4; ++i)
#pragma unroll
            for (int j = 0; j < 4; ++j)
                acc[i * 4 + j] = __builtin_amdgcn_mfma_scale_f32_16x16x128_f8f6f4(
                    a8[i], b8[j], acc[i * 4 + j], 0, 0, 0, SCALE_BYTE, 0, SCALE_BYTE);
        __syncthreads();   // all waves done reading before next stage
    }

    // epilogue. C layout: col = lane&15, row = (lane>>4)*4 + reg (16x16 shape)
    const int dp = dper[0];
#pragma unroll
    for (int i = 0; i < 4; ++i)
#pragma unroll
        for (int r = 0; r < 4; ++r) {
            const int gr   = qbase + wr * 64 + 16 * i + 4 * lquad + r;
            const int pcol = gr * dp - dbase;   // local col of positive, if here
            float e = 0.0f;
#pragma unroll
            for (int j = 0; j < 4; ++j) {
                float v = acc[i * 4 + j][r];
                if (wc * 64 + 16 * j + lm == pcol) pos[gr] = v * TEMP_INV;
                e += __expf(v * TEMP_INV);
            }
            e += __shfl_xor(e, 1);
            e += __shfl_xor(e, 2);
            e += __shfl_xor(e, 4);
            e += __shfl_xor(e, 8);
            if (lm == 0) atomicAdd(&rowsum[gr], e);
        }
}

// ---------------- final: loss = sum(log(rowsum) - pos)/B ----------------
__global__ void final_kernel(const float* __restrict__ rowsum,
                             const float* __restrict__ pos,
                             float* __restrict__ out, int B) {
    __shared__ float red[16];
    int tid = threadIdx.x;   // 1024 threads
    float s = 0.0f;
    for (int i = tid; i < B; i += blockDim.x)
        s += __logf(rowsum[i]) - pos[i];
    s += __shfl_xor(s, 32);
    s += __shfl_xor(s, 16);
    s += __shfl_xor(s, 8);
    s += __shfl_xor(s, 4);
    s += __shfl_xor(s, 2);
    s += __shfl_xor(s, 1);
    int w = tid >> 6, l = tid & 63;
    if (l == 0) red[w] = s;
    __syncthreads();
    if (tid == 0) {
        float t = 0.0f;
        int nw = blockDim.x >> 6;
        for (int i = 0; i < nw; ++i) t += red[i];
        out[0] = t / (float)B;
    }
}

extern "C" void kernel_launch(void* const* d_in, const int* in_sizes, int n_in,
                              void* d_out, int out_size, void* d_ws, size_t ws_size,
                              hipStream_t stream) {
    const float* Q   = (const float*)d_in[0];
    const float* Dm  = (const float*)d_in[1];
    const int* dper  = (const int*)d_in[2];
    float* out = (float*)d_out;

    const int DIM  = KD;
    const int B    = in_sizes[0] / DIM;   // 4096
    const int Ntot = in_sizes[1] / DIM;   // 8192

    unsigned int* Q8 = (unsigned int*)d_ws;
    unsigned int* D8 = Q8 + (size_t)B * DIM / 4;
    float* rowsum = (float*)(D8 + (size_t)Ntot * DIM / 4);
    float* pos = rowsum + B;

    const int qSlots = B * DIM / 16;            // 262144
    const int dSlots = Ntot * DIM / 16;         // 524288
    cvt_kernel<<<(qSlots + dSlots) / 256, 256, 0, stream>>>(
        Q, Dm, Q8, D8, rowsum, qSlots, B, DIM);

    dim3 grid(B / 128, Ntot / 256);
    gemm_expsum_kernel<<<grid, 512, 0, stream>>>(Q8, D8, dper, rowsum, pos, DIM);

    final_kernel<<<1, 1024, 0, stream>>>(rowsum, pos, out, B);
}

// Round 7
// 137.724 us; speedup vs baseline: 1.4470x; 1.0877x over previous
//
#include <hip/hip_runtime.h>

// InfoNCE loss:
//   loss = (1/B) * sum_i [ log(sum_j exp(Q_i . D_j / T)) - Q_i . D_{i*dp} / T ]
// Logits bounded (|logit| < ~10) -> no max-subtraction; per-row sum-exp is
// commutative -> atomicAdd merge across column-blocks.
//
// R7 = R4 (best: total 127us, GEMM 44.7us/1537TF) with ONE change:
//  - single-barrier double-buffered K-loop. R4: stage->barrier->compute->
//    barrier per kb (vmcnt(0) drain right after load issue = full load
//    latency exposed every iteration). R7: barrier->stage(kb+1,other buf)->
//    compute(kb); the top barrier proves buf[cur] landed (each wave's own
//    vmcnt(0)) AND all waves finished reading buf[1-cur] last iteration.
//    Loads now have a full compute phase in flight. LDS 32->64KB
//    (2 blocks/CU); R6 showed bigger tiles lose to occupancy, this keeps
//    the 256-thread 128x128 tile.
//  - cvt, epilogue, final: byte-identical to R4 (verified absmax 0.0).
//    NO device-scope fences in the GEMM (R5: L2-invalidate disaster).
//
// Tiled layout (per matrix): for 128-row block R, 128-wide k-block k0b:
//   16KB image = 16 chunks x 1KB. Chunk c = rg*2 + kh (rg=0..7 16-row group,
//   kh=0..1 64-col half); slot l (16B) holds
//   X[R*128 + rg*16 + (l&15)][k0b*128 + kh*64 + (l>>4)*16 .. +16]   (fp8)
//
// ws layout (~12.1 MB):
//   [0)       Q8  B*K fp8     (4 MB)
//   [B*K)     D8  N*K fp8     (8 MB)
//   [+N*K)    rowsum B f32    (16 KB)  zeroed by cvt kernel
//   [+B*4)    pos    B f32    (16 KB)  written by gemm epilogue

#define TEMP_INV 50.0f
#define PRESCALE 16.0f
#define SCALE_BYTE 123   // e8m0: 2^(123-127) = 2^-4 per operand
#define KD 1024          // DIM (fixed by problem shape)

typedef int   i32x4 __attribute__((ext_vector_type(4)));
typedef int   i32x8 __attribute__((ext_vector_type(8)));
typedef float f32x4 __attribute__((ext_vector_type(4)));

// ---------------- fp32 -> fp8 e4m3 (x16), pre-tiled; zero rowsum ----------
// One thread per 16B output slot (R4's verified cvt). Output stores are
// lane-linear; input reads are 64B/lane (4x float4, full-line utilization).
__global__ void cvt_kernel(const float* __restrict__ Q, const float* __restrict__ Dm,
                           unsigned int* __restrict__ Q8, unsigned int* __restrict__ D8,
                           float* __restrict__ rowsum, int qSlots, int B, int K) {
    const int gid = blockIdx.x * blockDim.x + threadIdx.x;
    if (gid < B) rowsum[gid] = 0.0f;
    const float* src;
    unsigned int* dst;
    int s;
    if (gid < qSlots) { src = Q;  dst = Q8; s = gid; }
    else              { src = Dm; dst = D8; s = gid - qSlots; }
    const int l   = s & 63;
    const int c   = (s >> 6) & 15;
    const int k0b = (s >> 10) & 7;
    const int R   = s >> 13;
    const int row = R * 128 + (c >> 1) * 16 + (l & 15);
    const int k   = k0b * 128 + (c & 1) * 64 + (l >> 4) * 16;
    const float* p = src + (size_t)row * K + k;
    unsigned int w[4];
#pragma unroll
    for (int d = 0; d < 4; ++d) {
        float4 v = *(const float4*)(p + d * 4);
        int t = __builtin_amdgcn_cvt_pk_fp8_f32(v.x * PRESCALE, v.y * PRESCALE, 0, false);
        t = __builtin_amdgcn_cvt_pk_fp8_f32(v.z * PRESCALE, v.w * PRESCALE, t, true);
        w[d] = (unsigned int)t;
    }
    *(uint4*)(dst + (size_t)s * 4) = make_uint4(w[0], w[1], w[2], w[3]);
}

// ---------------- fused MX-fp8 GEMM + row sum-exp + pos extraction --------
// grid (B/128, N/128), 256 threads (4 waves, 2x2 wave grid), BK=128,
// double-buffered LDS, one barrier per K-block.
__global__ __launch_bounds__(256, 2) void gemm_expsum_kernel(
        const unsigned int* __restrict__ Q8, const unsigned int* __restrict__ D8,
        const int* __restrict__ dper,
        float* __restrict__ rowsum, float* __restrict__ pos, int K) {
    __shared__ unsigned int Qs[2][4096];   // 2 x 16KB fragment-order images
    __shared__ unsigned int Ds[2][4096];

    const int tid   = threadIdx.x;
    const int wave  = tid >> 6;
    const int lane  = tid & 63;
    const int lquad = lane >> 4;
    const int lm    = lane & 15;
    const int qbase = blockIdx.x * 128;
    const int dbase = blockIdx.y * 128;
    const int KB    = K >> 7;           // 8 k-blocks

    // fragment-read dword offsets: chunk(rg, kh=lquad>>1)*256 + slot*4,
    // slot = ((lquad&1)*2 + t)*16 + lm
    const int slotofs = ((lquad & 1) * 32 + lm) * 4;   // t=0; t=1 adds 64
    const int aofs = ((wave >> 1) * 8 + (lquad >> 1)) * 256 + slotofs;
    const int bofs = ((wave & 1) * 8 + (lquad >> 1)) * 256 + slotofs;

    const unsigned int* Qg = Q8 + (size_t)blockIdx.x * KB * 4096;
    const unsigned int* Dg = D8 + (size_t)blockIdx.y * KB * 4096;

    // per-wave staging offsets (chunk c = 4*wave + q), lane-linear
    const int stg = (wave * 4) * 256 + lane * 4;

    f32x4 acc[16];
#pragma unroll
    for (int t = 0; t < 16; ++t) acc[t] = (f32x4){0.f, 0.f, 0.f, 0.f};

    // prologue: stage kb=0 into buffer 0
#pragma unroll
    for (int q = 0; q < 4; ++q) {
        __builtin_amdgcn_global_load_lds(
            (const __attribute__((address_space(1))) void*)(Qg + stg + q * 256),
            (__attribute__((address_space(3))) void*)(&Qs[0][0] + stg + q * 256),
            16, 0, 0);
        __builtin_amdgcn_global_load_lds(
            (const __attribute__((address_space(1))) void*)(Dg + stg + q * 256),
            (__attribute__((address_space(3))) void*)(&Ds[0][0] + stg + q * 256),
            16, 0, 0);
    }

    for (int kb = 0; kb < KB; ++kb) {
        const int cur = kb & 1;
        // barrier: (a) our stage(kb) loads into buf[cur] have landed
        // (compiler's vmcnt(0) drain -- issued a full compute phase ago),
        // (b) every wave finished reading buf[1-cur] in iteration kb-1.
        __syncthreads();

        if (kb + 1 < KB) {
            const int nxt = 1 - cur;
            const unsigned int* Qn = Qg + (kb + 1) * 4096;
            const unsigned int* Dn = Dg + (kb + 1) * 4096;
#pragma unroll
            for (int q = 0; q < 4; ++q) {
                __builtin_amdgcn_global_load_lds(
                    (const __attribute__((address_space(1))) void*)(Qn + stg + q * 256),
                    (__attribute__((address_space(3))) void*)(&Qs[nxt][0] + stg + q * 256),
                    16, 0, 0);
                __builtin_amdgcn_global_load_lds(
                    (const __attribute__((address_space(1))) void*)(Dn + stg + q * 256),
                    (__attribute__((address_space(3))) void*)(&Ds[nxt][0] + stg + q * 256),
                    16, 0, 0);
            }
        }

        i32x8 a8[4], b8[4];
#pragma unroll
        for (int i = 0; i < 4; ++i) {
            i32x4 lo = *(const i32x4*)(&Qs[cur][0] + aofs + i * 512);
            i32x4 hi = *(const i32x4*)(&Qs[cur][0] + aofs + i * 512 + 64);
            a8[i] = __builtin_shufflevector(lo, hi, 0, 1, 2, 3, 4, 5, 6, 7);
        }
#pragma unroll
        for (int j = 0; j < 4; ++j) {
            i32x4 lo = *(const i32x4*)(&Ds[cur][0] + bofs + j * 512);
            i32x4 hi = *(const i32x4*)(&Ds[cur][0] + bofs + j * 512 + 64);
            b8[j] = __builtin_shufflevector(lo, hi, 0, 1, 2, 3, 4, 5, 6, 7);
        }
#pragma unroll
        for (int i = 0; i < 4; ++i)
#pragma unroll
            for (int j = 0; j < 4; ++j)
                acc[i * 4 + j] = __builtin_amdgcn_mfma_scale_f32_16x16x128_f8f6f4(
                    a8[i], b8[j], acc[i * 4 + j], 0, 0, 0, SCALE_BYTE, 0, SCALE_BYTE);
    }

    // epilogue. C layout: col = lane&15, row = (lane>>4)*4 + reg (16x16 shape)
    const int dp = dper[0];
#pragma unroll
    for (int i = 0; i < 4; ++i)
#pragma unroll
        for (int r = 0; r < 4; ++r) {
            const int gr   = qbase + (wave >> 1) * 64 + 16 * i + 4 * lquad + r;
            const int pcol = gr * dp - dbase;   // local col of positive, if here
            float e = 0.0f;
#pragma unroll
            for (int j = 0; j < 4; ++j) {
                float v = acc[i * 4 + j][r];
                if ((wave & 1) * 64 + 16 * j + lm == pcol) pos[gr] = v * TEMP_INV;
                e += __expf(v * TEMP_INV);
            }
            e += __shfl_xor(e, 1);
            e += __shfl_xor(e, 2);
            e += __shfl_xor(e, 4);
            e += __shfl_xor(e, 8);
            if (lm == 0) atomicAdd(&rowsum[gr], e);
        }
}

// ---------------- final: loss = sum(log(rowsum) - pos)/B ----------------
__global__ void final_kernel(const float* __restrict__ rowsum,
                             const float* __restrict__ pos,
                             float* __restrict__ out, int B) {
    __shared__ float red[16];
    int tid = threadIdx.x;   // 1024 threads
    float s = 0.0f;
    for (int i = tid; i < B; i += blockDim.x)
        s += __logf(rowsum[i]) - pos[i];
    s += __shfl_xor(s, 32);
    s += __shfl_xor(s, 16);
    s += __shfl_xor(s, 8);
    s += __shfl_xor(s, 4);
    s += __shfl_xor(s, 2);
    s += __shfl_xor(s, 1);
    int w = tid >> 6, l = tid & 63;
    if (l == 0) red[w] = s;
    __syncthreads();
    if (tid == 0) {
        float t = 0.0f;
        int nw = blockDim.x >> 6;
        for (int i = 0; i < nw; ++i) t += red[i];
        out[0] = t / (float)B;
    }
}

extern "C" void kernel_launch(void* const* d_in, const int* in_sizes, int n_in,
                              void* d_out, int out_size, void* d_ws, size_t ws_size,
                              hipStream_t stream) {
    const float* Q   = (const float*)d_in[0];
    const float* Dm  = (const float*)d_in[1];
    const int* dper  = (const int*)d_in[2];
    float* out = (float*)d_out;

    const int DIM  = KD;
    const int B    = in_sizes[0] / DIM;   // 4096
    const int Ntot = in_sizes[1] / DIM;   // 8192

    unsigned int* Q8 = (unsigned int*)d_ws;
    unsigned int* D8 = Q8 + (size_t)B * DIM / 4;
    float* rowsum = (float*)(D8 + (size_t)Ntot * DIM / 4);
    float* pos = rowsum + B;

    const int qSlots = B * DIM / 16;            // 262144
    const int dSlots = Ntot * DIM / 16;         // 524288
    cvt_kernel<<<(qSlots + dSlots) / 256, 256, 0, stream>>>(
        Q, Dm, Q8, D8, rowsum, qSlots, B, DIM);

    dim3 grid(B / 128, Ntot / 128);
    gemm_expsum_kernel<<<grid, 256, 0, stream>>>(Q8, D8, dper, rowsum, pos, DIM);

    final_kernel<<<1, 1024, 0, stream>>>(rowsum, pos, out, B);
}